// Round 3
// baseline (385.819 us; speedup 1.0000x reference)
//
#include <hip/hip_runtime.h>
#include <hip/hip_bf16.h>

#define BB 32
#define RR 8192
#define EE 256
#define KK 64

#define BPB 16
#define ROWS_PB (RR / BPB)   // 512
#define TILE 32
#define NT (ROWS_PB / TILE)  // 16
#define RPAD 40              // pt row pad (elems): 80B rows -> 2-way-max banks

typedef __attribute__((ext_vector_type(8))) short short8;
typedef __attribute__((ext_vector_type(4))) float f32x4;

__device__ __forceinline__ unsigned short bf16rn(float v) {
    unsigned int u = __builtin_bit_cast(unsigned int, v);
    u = (u + 0x7FFFu + ((u >> 16) & 1u)) >> 16;   // RNE round to bf16
    return (unsigned short)u;
}
__device__ __forceinline__ float bf2f(unsigned short h) {
    unsigned int u = ((unsigned int)h) << 16;
    return __builtin_bit_cast(float, u);
}

__global__ __launch_bounds__(256, 2) void cluster_mfma(
    const float* __restrict__ x, const float* __restrict__ c,
    float* __restrict__ z, float* __restrict__ ws, int use_ws)
{
    __shared__ unsigned short xh[TILE * 256];   // 16KB, XOR-swizzled
    __shared__ unsigned short xl[TILE * 256];   // 16KB
    __shared__ unsigned short pth[KK * RPAD];   // 5KB  P^T hi
    __shared__ unsigned short ptl[KK * RPAD];   // 5KB  P^T lo
    __shared__ float redm[4][TILE];
    __shared__ float reds[4][TILE];

    char* const xhb = (char*)xh;
    char* const xlb = (char*)xl;

    const int t = threadIdx.x;
    const int w = t >> 6;        // wave 0..3
    const int l = t & 63;
    const int n = l & 15;        // fragment 16-lane index
    const int g = l >> 4;        // lane group 0..3
    const int b = blockIdx.y;
    const int blk = blockIdx.x;

    const float* xb = x + (size_t)b * RR * EE;

    // ---- persistent C fragments: wave w owns clusters [16w,16w+16) ----
    // A-frag convention: lane n = m (cluster), k-inner = 8*g + j (e-dim)
    short8 chf[8], clf[8];
    {
        const float* crow = c + (size_t)(16 * w + n) * EE + 8 * g;
        #pragma unroll
        for (int e0 = 0; e0 < 8; ++e0) {
            const float* p = crow + e0 * 32;
            float4 v0 = *(const float4*)(p);
            float4 v1 = *(const float4*)(p + 4);
            float vv[8] = {v0.x, v0.y, v0.z, v0.w, v1.x, v1.y, v1.z, v1.w};
            #pragma unroll
            for (int j = 0; j < 8; ++j) {
                unsigned short h = bf16rn(vv[j]);
                chf[e0][j] = (short)h;
                clf[e0][j] = (short)bf16rn(vv[j] - bf2f(h));
            }
        }
    }

    // z accumulators: wave w owns all 64 k  x  e in [64w, 64w+64)
    f32x4 zacc[4][4];
    #pragma unroll
    for (int i = 0; i < 4; ++i)
        #pragma unroll
        for (int j = 0; j < 4; ++j)
            zacc[i][j] = (f32x4){0.f, 0.f, 0.f, 0.f};

    const int rs = t >> 3;              // staging row 0..31
    const int qs = t & 7;               // staging sub-row chunk
    const int swzs = (rs & 7) << 4;
    const int swzn = (n & 7) << 4;

    for (int tile = 0; tile < NT; ++tile) {
        const int r0 = blk * ROWS_PB + tile * TILE;

        // ---------- stage x tile: fp32 global -> bf16 hi/lo LDS ----------
        {
            const float* srow = xb + (size_t)(r0 + rs) * EE;
            #pragma unroll
            for (int j4 = 0; j4 < 8; ++j4) {
                float4 v = *(const float4*)(srow + qs * 4 + j4 * 32);
                float vv[4] = {v.x, v.y, v.z, v.w};
                unsigned long long uh = 0, ul = 0;
                #pragma unroll
                for (int j = 0; j < 4; ++j) {
                    unsigned short h  = bf16rn(vv[j]);
                    unsigned short lo = bf16rn(vv[j] - bf2f(h));
                    uh |= ((unsigned long long)h)  << (16 * j);
                    ul |= ((unsigned long long)lo) << (16 * j);
                }
                const int off = (rs * 512 + qs * 8 + j4 * 64) ^ swzs;
                *(unsigned long long*)(xhb + off) = uh;
                *(unsigned long long*)(xlb + off) = ul;
            }
        }
        __syncthreads();

        // ---------- phase 1: S^T = C * x^T  (3-product bf16x2 split) ----------
        f32x4 sacc[2];
        sacc[0] = (f32x4){0.f, 0.f, 0.f, 0.f};
        sacc[1] = (f32x4){0.f, 0.f, 0.f, 0.f};
        #pragma unroll
        for (int e0 = 0; e0 < 8; ++e0) {
            #pragma unroll
            for (int cc = 0; cc < 2; ++cc) {
                const int row = cc * 16 + n;                      // x row (B n-index)
                const int off = (row * 512 + e0 * 64 + g * 16) ^ swzn;
                short8 xvh = *(const short8*)(xhb + off);         // e = 32*e0+8g+j
                short8 xvl = *(const short8*)(xlb + off);
                sacc[cc] = __builtin_amdgcn_mfma_f32_16x16x32_bf16(chf[e0], xvh, sacc[cc], 0, 0, 0);
                sacc[cc] = __builtin_amdgcn_mfma_f32_16x16x32_bf16(chf[e0], xvl, sacc[cc], 0, 0, 0);
                sacc[cc] = __builtin_amdgcn_mfma_f32_16x16x32_bf16(clf[e0], xvh, sacc[cc], 0, 0, 0);
            }
        }
        // lane holds S^T[k=16w+4g+reg][xrow=r0+16cc+n] in sacc[cc][reg]

        // ---------- softmax over k (all 64 clusters) ----------
        float mx[2], sm[2];
        #pragma unroll
        for (int cc = 0; cc < 2; ++cc) {
            float m = fmaxf(fmaxf(sacc[cc][0], sacc[cc][1]), fmaxf(sacc[cc][2], sacc[cc][3]));
            m = fmaxf(m, __shfl_xor(m, 16));
            m = fmaxf(m, __shfl_xor(m, 32));
            mx[cc] = m;
        }
        if (l < 16) { redm[w][n] = mx[0]; redm[w][16 + n] = mx[1]; }
        __syncthreads();
        float M[2];
        M[0] = fmaxf(fmaxf(redm[0][n], redm[1][n]), fmaxf(redm[2][n], redm[3][n]));
        M[1] = fmaxf(fmaxf(redm[0][16 + n], redm[1][16 + n]),
                     fmaxf(redm[2][16 + n], redm[3][16 + n]));
        float ex[2][4];
        #pragma unroll
        for (int cc = 0; cc < 2; ++cc) {
            float s = 0.f;
            #pragma unroll
            for (int r = 0; r < 4; ++r) { ex[cc][r] = __expf(sacc[cc][r] - M[cc]); s += ex[cc][r]; }
            s += __shfl_xor(s, 16);
            s += __shfl_xor(s, 32);
            sm[cc] = s;
        }
        if (l < 16) { reds[w][n] = sm[0]; reds[w][16 + n] = sm[1]; }
        __syncthreads();
        float R[2];
        R[0] = 1.0f / (reds[0][n] + reds[1][n] + reds[2][n] + reds[3][n]);
        R[1] = 1.0f / (reds[0][16 + n] + reds[1][16 + n] + reds[2][16 + n] + reds[3][16 + n]);

        // ---------- write P^T (hi/lo) to LDS ----------
        #pragma unroll
        for (int cc = 0; cc < 2; ++cc) {
            #pragma unroll
            for (int r = 0; r < 4; ++r) {
                float p = ex[cc][r] * R[cc];
                unsigned short ph = bf16rn(p);
                unsigned short pl = bf16rn(p - bf2f(ph));
                const int k  = 16 * w + 4 * g + r;
                const int rl = 16 * cc + n;
                pth[k * RPAD + rl] = ph;
                ptl[k * RPAD + rl] = pl;
            }
        }
        __syncthreads();

        // ---------- phase 3: zacc += P^T * x ----------
        short8 pah[4], pal[4];
        #pragma unroll
        for (int kc = 0; kc < 4; ++kc) {       // A-frag: lane n = cluster, kk = row 8g+j
            const int off = ((16 * kc + n) * RPAD + 8 * g) * 2;
            pah[kc] = *(const short8*)((char*)pth + off);
            pal[kc] = *(const short8*)((char*)ptl + off);
        }
        #pragma unroll
        for (int ecl = 0; ecl < 4; ++ecl) {
            const int ebyte = (64 * w + 16 * ecl + n) * 2;
            short8 xvh, xvl;
            #pragma unroll
            for (int j = 0; j < 8; ++j) {      // B-frag: lane n = e-col, kk = row 8g+j
                const int row = 8 * g + j;
                const int off = (row * 512 + ebyte) ^ ((row & 7) << 4);
                xvh[j] = (short)*(const unsigned short*)(xhb + off);
                xvl[j] = (short)*(const unsigned short*)(xlb + off);
            }
            #pragma unroll
            for (int kc = 0; kc < 4; ++kc) {
                zacc[kc][ecl] = __builtin_amdgcn_mfma_f32_16x16x32_bf16(pah[kc], xvh, zacc[kc][ecl], 0, 0, 0);
                zacc[kc][ecl] = __builtin_amdgcn_mfma_f32_16x16x32_bf16(pah[kc], xvl, zacc[kc][ecl], 0, 0, 0);
                zacc[kc][ecl] = __builtin_amdgcn_mfma_f32_16x16x32_bf16(pal[kc], xvh, zacc[kc][ecl], 0, 0, 0);
            }
        }
        __syncthreads();   // before next tile's staging overwrites xh/xl
    }

    // ---------- epilogue: z[k=16kc+4g+r][e=64w+16ecl+n] ----------
    if (use_ws) {
        float* dst = ws + (size_t)(b * BPB + blk) * KK * EE;
        #pragma unroll
        for (int kc = 0; kc < 4; ++kc)
            #pragma unroll
            for (int r = 0; r < 4; ++r)
                #pragma unroll
                for (int ecl = 0; ecl < 4; ++ecl)
                    dst[(size_t)(16 * kc + 4 * g + r) * EE + 64 * w + 16 * ecl + n] =
                        zacc[kc][ecl][r];
    } else {
        float* zb = z + (size_t)b * KK * EE;
        for (int kc = 0; kc < 4; ++kc)
            for (int r = 0; r < 4; ++r)
                for (int ecl = 0; ecl < 4; ++ecl)
                    atomicAdd(&zb[(size_t)(16 * kc + 4 * g + r) * EE + 64 * w + 16 * ecl + n],
                              zacc[kc][ecl][r]);
    }
}

__global__ __launch_bounds__(256) void reduce_partials(
    const float* __restrict__ ws, float* __restrict__ z)
{
    const int idx = blockIdx.x * 256 + threadIdx.x;   // over B*K*E = 524288
    const int b   = idx / (KK * EE);
    const int rem = idx - b * (KK * EE);
    const float* p = ws + (size_t)b * BPB * KK * EE + rem;
    float s = 0.0f;
    #pragma unroll
    for (int i = 0; i < BPB; ++i) s += p[(size_t)i * KK * EE];
    z[idx] = s;
}

extern "C" void kernel_launch(void* const* d_in, const int* in_sizes, int n_in,
                              void* d_out, int out_size, void* d_ws, size_t ws_size,
                              hipStream_t stream) {
    (void)in_sizes; (void)n_in;
    const float* x = (const float*)d_in[0];
    const float* c = (const float*)d_in[1];
    float* z  = (float*)d_out;
    float* ws = (float*)d_ws;

    const size_t need = (size_t)BB * BPB * KK * EE * sizeof(float);  // 33.5 MB
    const int use_ws = (ws_size >= need) ? 1 : 0;

    if (!use_ws)
        hipMemsetAsync(d_out, 0, (size_t)out_size * sizeof(float), stream);

    dim3 grid(BPB, BB);
    hipLaunchKernelGGL(cluster_mfma, grid, dim3(256), 0, stream, x, c, z, ws, use_ws);

    if (use_ws) {
        const int nel = BB * KK * EE;
        hipLaunchKernelGGL(reduce_partials, dim3(nel / 256), dim3(256), 0, stream, ws, z);
    }
}